// Round 3
// baseline (2156.390 us; speedup 1.0000x reference)
//
#include <hip/hip_runtime.h>
#include <hip/hip_bf16.h>
#include <math.h>

// ---------------------------------------------------------------------------
// GuoCapSAREncoder round 3: conv1 re-gridded for occupancy.
// conv1: block=(py,b) -> 2688 blocks, lanes=oc (LDS broadcast reads),
// w1 pre-transposed to [k][oc] for coalesced weight loads.
// conv2/convcaps: bf16 MFMA implicit GEMM (unchanged from round 2).
// ---------------------------------------------------------------------------

#define EPSF 1e-8f

typedef __bf16 bf16x8 __attribute__((ext_vector_type(8)));
typedef __bf16 bf16x4 __attribute__((ext_vector_type(4)));
typedef float floatx4 __attribute__((ext_vector_type(4)));

// ---- weight transposes ----------------------------------------------------
__global__ __launch_bounds__(256) void k_t_w1(const float* __restrict__ w1, float* __restrict__ w1T) {
    int i = blockIdx.x * 256 + threadIdx.x;          // 128*81 = 10368
    if (i >= 10368) return;
    int oc = i / 81, k = i % 81;
    w1T[k * 128 + oc] = w1[i];
}

__global__ __launch_bounds__(256) void k_t_w2b(const float* __restrict__ w2, __bf16* __restrict__ w2b) {
    int j = blockIdx.x * 256 + threadIdx.x;          // 204800
    if (j >= 204800) return;
    int khw = j / 8192, r2 = j & 8191;
    int oc = r2 >> 7, ic = r2 & 127;
    w2b[j] = (__bf16)w2[(oc * 128 + ic) * 25 + khw];
}

__global__ __launch_bounds__(256) void k_t_wcb(const float* __restrict__ wc, __bf16* __restrict__ wcb) {
    int j = blockIdx.x * 256 + threadIdx.x;          // 524288
    if (j >= 524288) return;
    int khw = j / 8192, r2 = j & 8191;
    int oc = r2 >> 6, ic = r2 & 63;
    wcb[j] = (__bf16)wc[(oc * 64 + ic) * 64 + khw];
}

// ---- conv1 9x9 + ReLU + maxpool2 -> h1n NHWC bf16 [b][42][42][128] --------
// block = (py, b); lanes = oc so xs reads are wave-uniform broadcasts.
// 21 pooled px per thread: 10 px-pairs + 1 remainder.
__global__ __launch_bounds__(256, 4) void k_conv1_pool(const float* __restrict__ x,
                                                       const float* __restrict__ w1T,
                                                       const float* __restrict__ b1,
                                                       __bf16* __restrict__ h1n) {
    __shared__ float xs[936];                        // 10 rows x 92 + OOB pad
    int py = blockIdx.x, b = blockIdx.y;
    int t = threadIdx.x;
    int oc = t & 127, half = t >> 7;
    const float* xb = x + (size_t)b * 8464 + 2 * py * 92;
    for (int j = t; j < 920; j += 256) xs[j] = xb[j];
    float wr[81];
#pragma unroll
    for (int k = 0; k < 81; ++k) wr[k] = w1T[k * 128 + oc];   // coalesced
    float bias = b1[oc];
    __syncthreads();

    int base = half * 21;
    size_t rowbase = (((size_t)b * 42 + py) * 42) * 128 + oc;
#pragma unroll 1
    for (int jp = 0; jp < 11; ++jp) {
        int px0 = base + (jp < 10 ? 2 * jp : 20);
        int ix0 = 2 * px0;
        float a0 = bias, a1 = bias, a2 = bias, a3 = bias;
        float a4 = bias, a5 = bias, a6 = bias, a7 = bias;
#pragma unroll
        for (int r = 0; r < 10; ++r) {
            float cur[12];
            const float2* rp = (const float2*)&xs[r * 92 + ix0];
#pragma unroll
            for (int j6 = 0; j6 < 6; ++j6) ((float2*)cur)[j6] = rp[j6];
            if (r < 9) {
#pragma unroll
                for (int kw = 0; kw < 9; ++kw) {
                    float w0 = wr[r * 9 + kw];
                    a0 = fmaf(cur[kw], w0, a0);
                    a1 = fmaf(cur[kw + 1], w0, a1);
                    a2 = fmaf(cur[kw + 2], w0, a2);
                    a3 = fmaf(cur[kw + 3], w0, a3);
                }
            }
            if (r >= 1) {
#pragma unroll
                for (int kw = 0; kw < 9; ++kw) {
                    float wv = wr[(r - 1) * 9 + kw];
                    a4 = fmaf(cur[kw], wv, a4);
                    a5 = fmaf(cur[kw + 1], wv, a5);
                    a6 = fmaf(cur[kw + 2], wv, a6);
                    a7 = fmaf(cur[kw + 3], wv, a7);
                }
            }
        }
        float m0 = fmaxf(fmaxf(a0, a1), fmaxf(a4, a5));
        h1n[rowbase + (size_t)px0 * 128] = (__bf16)fmaxf(m0, 0.f);
        if (jp < 10) {
            float m1 = fmaxf(fmaxf(a2, a3), fmaxf(a6, a7));
            h1n[rowbase + (size_t)(px0 + 1) * 128] = (__bf16)fmaxf(m1, 0.f);
        }
    }
}

// ---- conv2 5x5 via MFMA: h1n NHWC bf16 -> h2n NHWC bf16 [b][38][38][64] ---
__global__ __launch_bounds__(256, 2) void k_conv2(const __bf16* __restrict__ h1n,
                                                  const __bf16* __restrict__ w2b,
                                                  const float* __restrict__ b2,
                                                  __bf16* __restrict__ h2n) {
    __shared__ __bf16 ins[8 * 42 * 64];              // 43008 B
    int g = blockIdx.x, b = blockIdx.y;              // g in [0,10)
    int oh0 = g * 4;
    int t = threadIdx.x;
    int lane = t & 63, w = t >> 6;
    int wm = w & 1, wn = w >> 1;
    int cc = lane & 15, q = lane >> 4;

    int baseN[5], rv[5], cv[5], posv[5];
#pragma unroll
    for (int nt = 0; nt < 5; ++nt) {
        int p = wn * 80 + nt * 16 + cc;
        int pv = p < 152 ? p : 151;
        int r = pv / 38, c = pv - r * 38;
        posv[nt] = p; rv[nt] = r; cv[nt] = c;
        baseN[nt] = (r * 42 + c) * 128 + q * 16;     // bytes (64 ic * 2B)
    }
    floatx4 acc[2][5];
#pragma unroll
    for (int mt = 0; mt < 2; ++mt)
#pragma unroll
        for (int nt = 0; nt < 5; ++nt) acc[mt][nt] = (floatx4){0.f, 0.f, 0.f, 0.f};

    int ocA0 = wm * 32 + cc;
    for (int ic0 = 0; ic0 < 128; ic0 += 64) {
        __syncthreads();
        for (int j = t; j < 2688; j += 256) {        // 8 rows x 42 x 64ic bf16
            int lr = j / 336, rem = j - lr * 336;
            int ix = rem >> 3, icl0 = (rem & 7) * 8;
            int rg = oh0 + lr; if (rg > 41) rg = 41;
            const uint4* src = (const uint4*)(h1n + ((((size_t)b * 42 + rg) * 42 + ix) * 128 + ic0 + icl0));
            *(uint4*)((char*)ins + j * 16) = *src;
        }
        __syncthreads();
#pragma unroll
        for (int khw = 0; khw < 25; ++khw) {
            int kh = khw / 5, kw = khw - kh * 5;
            int boff = (kh * 42 + kw) * 128;
#pragma unroll
            for (int ks = 0; ks < 2; ++ks) {
                bf16x8 a0 = *(const bf16x8*)(w2b + (size_t)(khw * 64 + ocA0) * 128 + ic0 + ks * 32 + q * 8);
                bf16x8 a1 = *(const bf16x8*)(w2b + (size_t)(khw * 64 + ocA0 + 16) * 128 + ic0 + ks * 32 + q * 8);
#pragma unroll
                for (int nt = 0; nt < 5; ++nt) {
                    bf16x8 bfr = *(const bf16x8*)((char*)ins + baseN[nt] + boff + ks * 64);
                    acc[0][nt] = __builtin_amdgcn_mfma_f32_16x16x32_bf16(a0, bfr, acc[0][nt], 0, 0, 0);
                    acc[1][nt] = __builtin_amdgcn_mfma_f32_16x16x32_bf16(a1, bfr, acc[1][nt], 0, 0, 0);
                }
            }
        }
    }
#pragma unroll
    for (int mt = 0; mt < 2; ++mt) {
        int oc0 = wm * 32 + mt * 16 + q * 4;
        float4 bv = *(const float4*)(b2 + oc0);
#pragma unroll
        for (int nt = 0; nt < 5; ++nt) {
            int oh = oh0 + rv[nt];
            if (posv[nt] < 152 && oh < 38) {
                bf16x4 pk;
                pk.x = (__bf16)(acc[mt][nt][0] + bv.x);
                pk.y = (__bf16)(acc[mt][nt][1] + bv.y);
                pk.z = (__bf16)(acc[mt][nt][2] + bv.z);
                pk.w = (__bf16)(acc[mt][nt][3] + bv.w);
                *(bf16x4*)(h2n + ((((size_t)b * 38 + oh) * 38 + cv[nt]) * 64 + oc0)) = pk;
            }
        }
    }
}

// ---- caps conv 8x8 s2 via MFMA: h2n NHWC bf16 -> hcn NHWC fp32 ------------
__global__ __launch_bounds__(256, 2) void k_convcaps(const __bf16* __restrict__ h2n,
                                                     const __bf16* __restrict__ wcb,
                                                     const float* __restrict__ bc,
                                                     float* __restrict__ hcn) {
    __shared__ __bf16 ins[14 * 38 * 32];             // 34048 B
    int g = blockIdx.x, b = blockIdx.y;              // g in [0,4)
    int oh0 = g * 4;
    int t = threadIdx.x;
    int lane = t & 63, w = t >> 6;
    int cc = lane & 15, q = lane >> 4;

    int baseN[4];
#pragma unroll
    for (int nt = 0; nt < 4; ++nt)
        baseN[nt] = (2 * nt * 38 + 2 * cc) * 64 + q * 16;  // bytes (32 ic * 2B)

    floatx4 acc[2][4];
#pragma unroll
    for (int mt = 0; mt < 2; ++mt)
#pragma unroll
        for (int nt = 0; nt < 4; ++nt) acc[mt][nt] = (floatx4){0.f, 0.f, 0.f, 0.f};

    int ocA = w * 32 + cc;
    for (int ic0 = 0; ic0 < 64; ic0 += 32) {
        __syncthreads();
        for (int j = t; j < 2128; j += 256) {        // 14 rows x 38 x 32ic bf16
            int lr = j / 152, rem = j - lr * 152;
            int ix = rem >> 2, icl0 = (rem & 3) * 8;
            int rg = oh0 * 2 + lr;                   // max 24+13 = 37
            const uint4* src = (const uint4*)(h2n + ((((size_t)b * 38 + rg) * 38 + ix) * 64 + ic0 + icl0));
            *(uint4*)((char*)ins + j * 16) = *src;
        }
        __syncthreads();
#pragma unroll
        for (int khw = 0; khw < 64; ++khw) {
            int kh = khw >> 3, kw = khw & 7;
            int boff = (kh * 38 + kw) * 64;
            bf16x8 a0 = *(const bf16x8*)(wcb + (size_t)(khw * 128 + ocA) * 64 + ic0 + q * 8);
            bf16x8 a1 = *(const bf16x8*)(wcb + (size_t)(khw * 128 + ocA + 16) * 64 + ic0 + q * 8);
#pragma unroll
            for (int nt = 0; nt < 4; ++nt) {
                bf16x8 bfr = *(const bf16x8*)((char*)ins + baseN[nt] + boff);
                acc[0][nt] = __builtin_amdgcn_mfma_f32_16x16x32_bf16(a0, bfr, acc[0][nt], 0, 0, 0);
                acc[1][nt] = __builtin_amdgcn_mfma_f32_16x16x32_bf16(a1, bfr, acc[1][nt], 0, 0, 0);
            }
        }
    }
#pragma unroll
    for (int mt = 0; mt < 2; ++mt) {
        int oc0 = w * 32 + mt * 16 + q * 4;
        float4 bv = *(const float4*)(bc + oc0);
#pragma unroll
        for (int nt = 0; nt < 4; ++nt) {
            int p = nt * 16 + cc;
            int oh = oh0 + (p >> 4), ow = p & 15;
            float4 st;
            st.x = acc[mt][nt][0] + bv.x;
            st.y = acc[mt][nt][1] + bv.y;
            st.z = acc[mt][nt][2] + bv.z;
            st.w = acc[mt][nt][3] + bv.w;
            *(float4*)(hcn + (((size_t)b * 256 + oh * 16 + ow) * 128 + oc0)) = st;
        }
    }
}

// ---- primary-capsule reorder + squash: hcn NHWC -> u:[64,1024,32] ---------
__global__ __launch_bounds__(256) void k_squash(const float* __restrict__ hcn,
                                                float* __restrict__ u) {
    int b = blockIdx.x, capg = blockIdx.y;           // capg in [0,128)
    int t = threadIdx.x;
    int capl = t >> 5, i = t & 31;
    int cap = capg * 8 + capl;
    int ct = cap >> 8, rem = cap & 255;              // rem = y*16+x
    float val = hcn[((size_t)b * 256 + rem) * 128 + ct * 32 + i];
    float s = val * val;
#pragma unroll
    for (int off = 1; off < 32; off <<= 1) s += __shfl_xor(s, off, 64);
    float scale = (s / (1.f + s)) / sqrtf(s + EPSF);
    u[((size_t)b * 1024 + cap) * 32 + i] = val * scale;
}

// ---- u_hat: u:[64,1024,32] Wr:[1024,10,16,32] -> uhT:[b][t][o][p] ---------
__global__ __launch_bounds__(256) void k_uhat(const float* __restrict__ u,
                                              const float* __restrict__ Wr,
                                              float* __restrict__ uhT) {
    int pt = blockIdx.x;   // 16 tiles of 64 p
    int ts = blockIdx.y;   // 10
    int bz = blockIdx.z;   // 4 groups of 16 b
    int t = threadIdx.x;
    int p = pt * 64 + (t & 63);
    int q = t >> 6;
    for (int b = bz * 16 + q; b < bz * 16 + 16; b += 4) {
        float4 uu[8];
        const float4* up = (const float4*)(u + ((size_t)b * 1024 + p) * 32);
#pragma unroll
        for (int j = 0; j < 8; ++j) uu[j] = up[j];
#pragma unroll
        for (int o = 0; o < 16; ++o) {
            const float4* wp = (const float4*)(Wr + (((size_t)p * 10 + ts) * 16 + o) * 32);
            float4 a = {0.f, 0.f, 0.f, 0.f};
#pragma unroll
            for (int j = 0; j < 8; ++j) {
                float4 w4 = wp[j];
                a.x = fmaf(uu[j].x, w4.x, a.x);
                a.y = fmaf(uu[j].y, w4.y, a.y);
                a.z = fmaf(uu[j].z, w4.z, a.z);
                a.w = fmaf(uu[j].w, w4.w, a.w);
            }
            uhT[(((size_t)b * 10 + ts) * 16 + o) * 1024 + p] = (a.x + a.y) + (a.z + a.w);
        }
    }
}

// ---- routing kernels ------------------------------------------------------
__global__ __launch_bounds__(256) void k_route_s(const float* __restrict__ uhT,
                                                 const float* __restrict__ bl,
                                                 float* __restrict__ vout,
                                                 float* __restrict__ out,
                                                 int first, int last) {
    __shared__ float sred[4][16];
    int b = blockIdx.x, tt = blockIdx.y;
    int t = threadIdx.x;
    float acc[16];
#pragma unroll
    for (int o = 0; o < 16; ++o) acc[o] = 0.f;
    const float* blb = bl + b * 10240;
    const float* uhb = uhT + ((size_t)b * 10 + tt) * 16384;
    for (int p = t; p < 1024; p += 256) {
        float c;
        if (first) {
            c = 0.1f;
        } else {
            float den = 0.f, et = 0.f;
#pragma unroll
            for (int tp = 0; tp < 10; ++tp) {
                float e = expf(blb[tp * 1024 + p]);
                den += e;
                if (tp == tt) et = e;
            }
            c = et / den;
        }
#pragma unroll
        for (int o = 0; o < 16; ++o)
            acc[o] = fmaf(c, uhb[o * 1024 + p], acc[o]);
    }
    int lane = t & 63, wid = t >> 6;
#pragma unroll
    for (int o = 0; o < 16; ++o) {
        float v = acc[o];
#pragma unroll
        for (int off = 32; off >= 1; off >>= 1) v += __shfl_xor(v, off, 64);
        if (lane == 0) sred[wid][o] = v;
    }
    __syncthreads();
    if (t < 16) {
        float s = (sred[0][t] + sred[1][t]) + (sred[2][t] + sred[3][t]);
        float n2 = s * s;
#pragma unroll
        for (int off = 1; off < 16; off <<= 1) n2 += __shfl_xor(n2, off, 16);
        float scale = (n2 / (1.f + n2)) / sqrtf(n2 + EPSF);
        vout[(b * 10 + tt) * 16 + t] = s * scale;
        if (last && t == 0) {
            float sv2 = n2 * scale * scale;
            out[b * 10 + tt] = sqrtf(sv2 + EPSF);
        }
    }
}

__global__ __launch_bounds__(256) void k_route_b(const float* __restrict__ uhT,
                                                 const float* __restrict__ vv,
                                                 float* __restrict__ bl,
                                                 int first) {
    __shared__ float vs[16];
    int b = blockIdx.x, tt = blockIdx.y;
    int t = threadIdx.x;
    if (t < 16) vs[t] = vv[(b * 10 + tt) * 16 + t];
    __syncthreads();
    const float* uhb = uhT + ((size_t)b * 10 + tt) * 16384;
    float* blb = bl + (b * 10 + tt) * 1024;
    for (int p = t; p < 1024; p += 256) {
        float d = 0.f;
#pragma unroll
        for (int o = 0; o < 16; ++o) d = fmaf(uhb[o * 1024 + p], vs[o], d);
        blb[p] = first ? d : (blb[p] + d);
    }
}

// ---------------------------------------------------------------------------
extern "C" void kernel_launch(void* const* d_in, const int* in_sizes, int n_in,
                              void* d_out, int out_size, void* d_ws, size_t ws_size,
                              hipStream_t stream) {
    const float* x  = (const float*)d_in[0];
    const float* w1 = (const float*)d_in[1];
    const float* b1 = (const float*)d_in[2];
    const float* w2 = (const float*)d_in[3];
    const float* b2 = (const float*)d_in[4];
    const float* wc = (const float*)d_in[5];
    const float* bc = (const float*)d_in[6];
    const float* Wr = (const float*)d_in[7];
    float* out = (float*)d_out;
    float* ws  = (float*)d_ws;

    // workspace layout (float offsets)
    __bf16* w2b = (__bf16*)(ws);                  // 204800 bf16 = 102400 f
    __bf16* wcb = (__bf16*)(ws + 102400);         // 524288 bf16 = 262144 f
    float*  w1T = ws + 364544;                    // 10368 f (pad to 10496)
    __bf16* h1n = (__bf16*)(ws + 375040);         // 14450688 bf16 = 7225344 f
    __bf16* h2n = (__bf16*)(ws + 7600384);        // 5914624 bf16 = 2957312 f
    float*  hcn = ws + 10557696;                  // 2097152 f
    float*  u   = ws + 12654848;                  // 2097152 f
    float*  bl  = ws + 14752000;                  // 655360 f
    float*  vv  = ws + 15407360;                  // 10240 f -> 15417600 f (61.7 MB)
    float*  uhT = ws + 375040;                    // overlays h1n+h2n+hcn (dead by k_uhat)

    k_t_w1<<<41, 256, 0, stream>>>(w1, w1T);
    k_t_w2b<<<800, 256, 0, stream>>>(w2, w2b);
    k_t_wcb<<<2048, 256, 0, stream>>>(wc, wcb);
    k_conv1_pool<<<dim3(42, 64), 256, 0, stream>>>(x, w1T, b1, h1n);
    k_conv2<<<dim3(10, 64), 256, 0, stream>>>(h1n, w2b, b2, h2n);
    k_convcaps<<<dim3(4, 64), 256, 0, stream>>>(h2n, wcb, bc, hcn);
    k_squash<<<dim3(64, 128), 256, 0, stream>>>(hcn, u);
    k_uhat<<<dim3(16, 10, 4), 256, 0, stream>>>(u, Wr, uhT);
    k_route_s<<<dim3(64, 10), 256, 0, stream>>>(uhT, bl, vv, out, 1, 0);
    k_route_b<<<dim3(64, 10), 256, 0, stream>>>(uhT, vv, bl, 1);
    k_route_s<<<dim3(64, 10), 256, 0, stream>>>(uhT, bl, vv, out, 0, 0);
    k_route_b<<<dim3(64, 10), 256, 0, stream>>>(uhT, vv, bl, 0);
    k_route_s<<<dim3(64, 10), 256, 0, stream>>>(uhT, bl, vv, out, 0, 1);
}

// Round 4
// 588.472 us; speedup vs baseline: 3.6644x; 3.6644x over previous
//
#include <hip/hip_runtime.h>
#include <hip/hip_bf16.h>
#include <math.h>

// ---------------------------------------------------------------------------
// GuoCapSAREncoder round 4: conv1 = round-3 grid (2688 blocks) but
// __launch_bounds__(256,2) -> VGPR 128, no scratch spill (round 3's (256,4)
// capped VGPR at 64 and spilled wr[81] -> 7 GB HBM scratch traffic).
// conv2/convcaps: bf16 MFMA implicit GEMM (unchanged).
// ---------------------------------------------------------------------------

#define EPSF 1e-8f

typedef __bf16 bf16x8 __attribute__((ext_vector_type(8)));
typedef __bf16 bf16x4 __attribute__((ext_vector_type(4)));
typedef float floatx4 __attribute__((ext_vector_type(4)));

// ---- weight transposes ----------------------------------------------------
__global__ __launch_bounds__(256) void k_t_w1(const float* __restrict__ w1, float* __restrict__ w1T) {
    int i = blockIdx.x * 256 + threadIdx.x;          // 128*81 = 10368
    if (i >= 10368) return;
    int oc = i / 81, k = i % 81;
    w1T[k * 128 + oc] = w1[i];
}

__global__ __launch_bounds__(256) void k_t_w2b(const float* __restrict__ w2, __bf16* __restrict__ w2b) {
    int j = blockIdx.x * 256 + threadIdx.x;          // 204800
    if (j >= 204800) return;
    int khw = j / 8192, r2 = j & 8191;
    int oc = r2 >> 7, ic = r2 & 127;
    w2b[j] = (__bf16)w2[(oc * 128 + ic) * 25 + khw];
}

__global__ __launch_bounds__(256) void k_t_wcb(const float* __restrict__ wc, __bf16* __restrict__ wcb) {
    int j = blockIdx.x * 256 + threadIdx.x;          // 524288
    if (j >= 524288) return;
    int khw = j / 8192, r2 = j & 8191;
    int oc = r2 >> 6, ic = r2 & 63;
    wcb[j] = (__bf16)wc[(oc * 64 + ic) * 64 + khw];
}

// ---- conv1 9x9 + ReLU + maxpool2 -> h1n NHWC bf16 [b][42][42][128] --------
// block = (py, b); lanes = oc so xs reads are wave-uniform broadcasts.
// 21 pooled px per thread: 10 px-pairs + 1 remainder.
// launch_bounds (256,2): VGPR cap 128 -- wr[81] fits, NO spill (round-3 bug).
__global__ __launch_bounds__(256, 2) void k_conv1_pool(const float* __restrict__ x,
                                                       const float* __restrict__ w1T,
                                                       const float* __restrict__ b1,
                                                       __bf16* __restrict__ h1n) {
    __shared__ float xs[936];                        // 10 rows x 92 + OOB pad
    int py = blockIdx.x, b = blockIdx.y;
    int t = threadIdx.x;
    int oc = t & 127, half = t >> 7;
    const float* xb = x + (size_t)b * 8464 + 2 * py * 92;
    for (int j = t; j < 920; j += 256) xs[j] = xb[j];
    float wr[81];
#pragma unroll
    for (int k = 0; k < 81; ++k) wr[k] = w1T[k * 128 + oc];   // coalesced
    float bias = b1[oc];
    __syncthreads();

    int base = half * 21;
    size_t rowbase = (((size_t)b * 42 + py) * 42) * 128 + oc;
#pragma unroll 1
    for (int jp = 0; jp < 11; ++jp) {
        int px0 = base + (jp < 10 ? 2 * jp : 20);
        int ix0 = 2 * px0;
        float a0 = bias, a1 = bias, a2 = bias, a3 = bias;
        float a4 = bias, a5 = bias, a6 = bias, a7 = bias;
#pragma unroll
        for (int r = 0; r < 10; ++r) {
            float cur[12];
            const float2* rp = (const float2*)&xs[r * 92 + ix0];
#pragma unroll
            for (int j6 = 0; j6 < 6; ++j6) ((float2*)cur)[j6] = rp[j6];
            if (r < 9) {
#pragma unroll
                for (int kw = 0; kw < 9; ++kw) {
                    float w0 = wr[r * 9 + kw];
                    a0 = fmaf(cur[kw], w0, a0);
                    a1 = fmaf(cur[kw + 1], w0, a1);
                    a2 = fmaf(cur[kw + 2], w0, a2);
                    a3 = fmaf(cur[kw + 3], w0, a3);
                }
            }
            if (r >= 1) {
#pragma unroll
                for (int kw = 0; kw < 9; ++kw) {
                    float wv = wr[(r - 1) * 9 + kw];
                    a4 = fmaf(cur[kw], wv, a4);
                    a5 = fmaf(cur[kw + 1], wv, a5);
                    a6 = fmaf(cur[kw + 2], wv, a6);
                    a7 = fmaf(cur[kw + 3], wv, a7);
                }
            }
        }
        float m0 = fmaxf(fmaxf(a0, a1), fmaxf(a4, a5));
        h1n[rowbase + (size_t)px0 * 128] = (__bf16)fmaxf(m0, 0.f);
        if (jp < 10) {
            float m1 = fmaxf(fmaxf(a2, a3), fmaxf(a6, a7));
            h1n[rowbase + (size_t)(px0 + 1) * 128] = (__bf16)fmaxf(m1, 0.f);
        }
    }
}

// ---- conv2 5x5 via MFMA: h1n NHWC bf16 -> h2n NHWC bf16 [b][38][38][64] ---
__global__ __launch_bounds__(256, 2) void k_conv2(const __bf16* __restrict__ h1n,
                                                  const __bf16* __restrict__ w2b,
                                                  const float* __restrict__ b2,
                                                  __bf16* __restrict__ h2n) {
    __shared__ __bf16 ins[8 * 42 * 64];              // 43008 B
    int g = blockIdx.x, b = blockIdx.y;              // g in [0,10)
    int oh0 = g * 4;
    int t = threadIdx.x;
    int lane = t & 63, w = t >> 6;
    int wm = w & 1, wn = w >> 1;
    int cc = lane & 15, q = lane >> 4;

    int baseN[5], rv[5], cv[5], posv[5];
#pragma unroll
    for (int nt = 0; nt < 5; ++nt) {
        int p = wn * 80 + nt * 16 + cc;
        int pv = p < 152 ? p : 151;
        int r = pv / 38, c = pv - r * 38;
        posv[nt] = p; rv[nt] = r; cv[nt] = c;
        baseN[nt] = (r * 42 + c) * 128 + q * 16;     // bytes (64 ic * 2B)
    }
    floatx4 acc[2][5];
#pragma unroll
    for (int mt = 0; mt < 2; ++mt)
#pragma unroll
        for (int nt = 0; nt < 5; ++nt) acc[mt][nt] = (floatx4){0.f, 0.f, 0.f, 0.f};

    int ocA0 = wm * 32 + cc;
    for (int ic0 = 0; ic0 < 128; ic0 += 64) {
        __syncthreads();
        for (int j = t; j < 2688; j += 256) {        // 8 rows x 42 x 64ic bf16
            int lr = j / 336, rem = j - lr * 336;
            int ix = rem >> 3, icl0 = (rem & 7) * 8;
            int rg = oh0 + lr; if (rg > 41) rg = 41;
            const uint4* src = (const uint4*)(h1n + ((((size_t)b * 42 + rg) * 42 + ix) * 128 + ic0 + icl0));
            *(uint4*)((char*)ins + j * 16) = *src;
        }
        __syncthreads();
#pragma unroll
        for (int khw = 0; khw < 25; ++khw) {
            int kh = khw / 5, kw = khw - kh * 5;
            int boff = (kh * 42 + kw) * 128;
#pragma unroll
            for (int ks = 0; ks < 2; ++ks) {
                bf16x8 a0 = *(const bf16x8*)(w2b + (size_t)(khw * 64 + ocA0) * 128 + ic0 + ks * 32 + q * 8);
                bf16x8 a1 = *(const bf16x8*)(w2b + (size_t)(khw * 64 + ocA0 + 16) * 128 + ic0 + ks * 32 + q * 8);
#pragma unroll
                for (int nt = 0; nt < 5; ++nt) {
                    bf16x8 bfr = *(const bf16x8*)((char*)ins + baseN[nt] + boff + ks * 64);
                    acc[0][nt] = __builtin_amdgcn_mfma_f32_16x16x32_bf16(a0, bfr, acc[0][nt], 0, 0, 0);
                    acc[1][nt] = __builtin_amdgcn_mfma_f32_16x16x32_bf16(a1, bfr, acc[1][nt], 0, 0, 0);
                }
            }
        }
    }
#pragma unroll
    for (int mt = 0; mt < 2; ++mt) {
        int oc0 = wm * 32 + mt * 16 + q * 4;
        float4 bv = *(const float4*)(b2 + oc0);
#pragma unroll
        for (int nt = 0; nt < 5; ++nt) {
            int oh = oh0 + rv[nt];
            if (posv[nt] < 152 && oh < 38) {
                bf16x4 pk;
                pk.x = (__bf16)(acc[mt][nt][0] + bv.x);
                pk.y = (__bf16)(acc[mt][nt][1] + bv.y);
                pk.z = (__bf16)(acc[mt][nt][2] + bv.z);
                pk.w = (__bf16)(acc[mt][nt][3] + bv.w);
                *(bf16x4*)(h2n + ((((size_t)b * 38 + oh) * 38 + cv[nt]) * 64 + oc0)) = pk;
            }
        }
    }
}

// ---- caps conv 8x8 s2 via MFMA: h2n NHWC bf16 -> hcn NHWC fp32 ------------
__global__ __launch_bounds__(256, 2) void k_convcaps(const __bf16* __restrict__ h2n,
                                                     const __bf16* __restrict__ wcb,
                                                     const float* __restrict__ bc,
                                                     float* __restrict__ hcn) {
    __shared__ __bf16 ins[14 * 38 * 32];             // 34048 B
    int g = blockIdx.x, b = blockIdx.y;              // g in [0,4)
    int oh0 = g * 4;
    int t = threadIdx.x;
    int lane = t & 63, w = t >> 6;
    int cc = lane & 15, q = lane >> 4;

    int baseN[4];
#pragma unroll
    for (int nt = 0; nt < 4; ++nt)
        baseN[nt] = (2 * nt * 38 + 2 * cc) * 64 + q * 16;  // bytes (32 ic * 2B)

    floatx4 acc[2][4];
#pragma unroll
    for (int mt = 0; mt < 2; ++mt)
#pragma unroll
        for (int nt = 0; nt < 4; ++nt) acc[mt][nt] = (floatx4){0.f, 0.f, 0.f, 0.f};

    int ocA = w * 32 + cc;
    for (int ic0 = 0; ic0 < 64; ic0 += 32) {
        __syncthreads();
        for (int j = t; j < 2128; j += 256) {        // 14 rows x 38 x 32ic bf16
            int lr = j / 152, rem = j - lr * 152;
            int ix = rem >> 2, icl0 = (rem & 3) * 8;
            int rg = oh0 * 2 + lr;                   // max 24+13 = 37
            const uint4* src = (const uint4*)(h2n + ((((size_t)b * 38 + rg) * 38 + ix) * 64 + ic0 + icl0));
            *(uint4*)((char*)ins + j * 16) = *src;
        }
        __syncthreads();
#pragma unroll
        for (int khw = 0; khw < 64; ++khw) {
            int kh = khw >> 3, kw = khw & 7;
            int boff = (kh * 38 + kw) * 64;
            bf16x8 a0 = *(const bf16x8*)(wcb + (size_t)(khw * 128 + ocA) * 64 + ic0 + q * 8);
            bf16x8 a1 = *(const bf16x8*)(wcb + (size_t)(khw * 128 + ocA + 16) * 64 + ic0 + q * 8);
#pragma unroll
            for (int nt = 0; nt < 4; ++nt) {
                bf16x8 bfr = *(const bf16x8*)((char*)ins + baseN[nt] + boff);
                acc[0][nt] = __builtin_amdgcn_mfma_f32_16x16x32_bf16(a0, bfr, acc[0][nt], 0, 0, 0);
                acc[1][nt] = __builtin_amdgcn_mfma_f32_16x16x32_bf16(a1, bfr, acc[1][nt], 0, 0, 0);
            }
        }
    }
#pragma unroll
    for (int mt = 0; mt < 2; ++mt) {
        int oc0 = w * 32 + mt * 16 + q * 4;
        float4 bv = *(const float4*)(bc + oc0);
#pragma unroll
        for (int nt = 0; nt < 4; ++nt) {
            int p = nt * 16 + cc;
            int oh = oh0 + (p >> 4), ow = p & 15;
            float4 st;
            st.x = acc[mt][nt][0] + bv.x;
            st.y = acc[mt][nt][1] + bv.y;
            st.z = acc[mt][nt][2] + bv.z;
            st.w = acc[mt][nt][3] + bv.w;
            *(float4*)(hcn + (((size_t)b * 256 + oh * 16 + ow) * 128 + oc0)) = st;
        }
    }
}

// ---- primary-capsule reorder + squash: hcn NHWC -> u:[64,1024,32] ---------
__global__ __launch_bounds__(256) void k_squash(const float* __restrict__ hcn,
                                                float* __restrict__ u) {
    int b = blockIdx.x, capg = blockIdx.y;           // capg in [0,128)
    int t = threadIdx.x;
    int capl = t >> 5, i = t & 31;
    int cap = capg * 8 + capl;
    int ct = cap >> 8, rem = cap & 255;              // rem = y*16+x
    float val = hcn[((size_t)b * 256 + rem) * 128 + ct * 32 + i];
    float s = val * val;
#pragma unroll
    for (int off = 1; off < 32; off <<= 1) s += __shfl_xor(s, off, 64);
    float scale = (s / (1.f + s)) / sqrtf(s + EPSF);
    u[((size_t)b * 1024 + cap) * 32 + i] = val * scale;
}

// ---- u_hat: u:[64,1024,32] Wr:[1024,10,16,32] -> uhT:[b][t][o][p] ---------
__global__ __launch_bounds__(256) void k_uhat(const float* __restrict__ u,
                                              const float* __restrict__ Wr,
                                              float* __restrict__ uhT) {
    int pt = blockIdx.x;   // 16 tiles of 64 p
    int ts = blockIdx.y;   // 10
    int bz = blockIdx.z;   // 4 groups of 16 b
    int t = threadIdx.x;
    int p = pt * 64 + (t & 63);
    int q = t >> 6;
    for (int b = bz * 16 + q; b < bz * 16 + 16; b += 4) {
        float4 uu[8];
        const float4* up = (const float4*)(u + ((size_t)b * 1024 + p) * 32);
#pragma unroll
        for (int j = 0; j < 8; ++j) uu[j] = up[j];
#pragma unroll
        for (int o = 0; o < 16; ++o) {
            const float4* wp = (const float4*)(Wr + (((size_t)p * 10 + ts) * 16 + o) * 32);
            float4 a = {0.f, 0.f, 0.f, 0.f};
#pragma unroll
            for (int j = 0; j < 8; ++j) {
                float4 w4 = wp[j];
                a.x = fmaf(uu[j].x, w4.x, a.x);
                a.y = fmaf(uu[j].y, w4.y, a.y);
                a.z = fmaf(uu[j].z, w4.z, a.z);
                a.w = fmaf(uu[j].w, w4.w, a.w);
            }
            uhT[(((size_t)b * 10 + ts) * 16 + o) * 1024 + p] = (a.x + a.y) + (a.z + a.w);
        }
    }
}

// ---- routing kernels ------------------------------------------------------
__global__ __launch_bounds__(256) void k_route_s(const float* __restrict__ uhT,
                                                 const float* __restrict__ bl,
                                                 float* __restrict__ vout,
                                                 float* __restrict__ out,
                                                 int first, int last) {
    __shared__ float sred[4][16];
    int b = blockIdx.x, tt = blockIdx.y;
    int t = threadIdx.x;
    float acc[16];
#pragma unroll
    for (int o = 0; o < 16; ++o) acc[o] = 0.f;
    const float* blb = bl + b * 10240;
    const float* uhb = uhT + ((size_t)b * 10 + tt) * 16384;
    for (int p = t; p < 1024; p += 256) {
        float c;
        if (first) {
            c = 0.1f;
        } else {
            float den = 0.f, et = 0.f;
#pragma unroll
            for (int tp = 0; tp < 10; ++tp) {
                float e = expf(blb[tp * 1024 + p]);
                den += e;
                if (tp == tt) et = e;
            }
            c = et / den;
        }
#pragma unroll
        for (int o = 0; o < 16; ++o)
            acc[o] = fmaf(c, uhb[o * 1024 + p], acc[o]);
    }
    int lane = t & 63, wid = t >> 6;
#pragma unroll
    for (int o = 0; o < 16; ++o) {
        float v = acc[o];
#pragma unroll
        for (int off = 32; off >= 1; off >>= 1) v += __shfl_xor(v, off, 64);
        if (lane == 0) sred[wid][o] = v;
    }
    __syncthreads();
    if (t < 16) {
        float s = (sred[0][t] + sred[1][t]) + (sred[2][t] + sred[3][t]);
        float n2 = s * s;
#pragma unroll
        for (int off = 1; off < 16; off <<= 1) n2 += __shfl_xor(n2, off, 16);
        float scale = (n2 / (1.f + n2)) / sqrtf(n2 + EPSF);
        vout[(b * 10 + tt) * 16 + t] = s * scale;
        if (last && t == 0) {
            float sv2 = n2 * scale * scale;
            out[b * 10 + tt] = sqrtf(sv2 + EPSF);
        }
    }
}

__global__ __launch_bounds__(256) void k_route_b(const float* __restrict__ uhT,
                                                 const float* __restrict__ vv,
                                                 float* __restrict__ bl,
                                                 int first) {
    __shared__ float vs[16];
    int b = blockIdx.x, tt = blockIdx.y;
    int t = threadIdx.x;
    if (t < 16) vs[t] = vv[(b * 10 + tt) * 16 + t];
    __syncthreads();
    const float* uhb = uhT + ((size_t)b * 10 + tt) * 16384;
    float* blb = bl + (b * 10 + tt) * 1024;
    for (int p = t; p < 1024; p += 256) {
        float d = 0.f;
#pragma unroll
        for (int o = 0; o < 16; ++o) d = fmaf(uhb[o * 1024 + p], vs[o], d);
        blb[p] = first ? d : (blb[p] + d);
    }
}

// ---------------------------------------------------------------------------
extern "C" void kernel_launch(void* const* d_in, const int* in_sizes, int n_in,
                              void* d_out, int out_size, void* d_ws, size_t ws_size,
                              hipStream_t stream) {
    const float* x  = (const float*)d_in[0];
    const float* w1 = (const float*)d_in[1];
    const float* b1 = (const float*)d_in[2];
    const float* w2 = (const float*)d_in[3];
    const float* b2 = (const float*)d_in[4];
    const float* wc = (const float*)d_in[5];
    const float* bc = (const float*)d_in[6];
    const float* Wr = (const float*)d_in[7];
    float* out = (float*)d_out;
    float* ws  = (float*)d_ws;

    // workspace layout (float offsets)
    __bf16* w2b = (__bf16*)(ws);                  // 204800 bf16 = 102400 f
    __bf16* wcb = (__bf16*)(ws + 102400);         // 524288 bf16 = 262144 f
    float*  w1T = ws + 364544;                    // 10368 f (pad to 10496)
    __bf16* h1n = (__bf16*)(ws + 375040);         // 14450688 bf16 = 7225344 f
    __bf16* h2n = (__bf16*)(ws + 7600384);        // 5914624 bf16 = 2957312 f
    float*  hcn = ws + 10557696;                  // 2097152 f
    float*  u   = ws + 12654848;                  // 2097152 f
    float*  bl  = ws + 14752000;                  // 655360 f
    float*  vv  = ws + 15407360;                  // 10240 f -> 15417600 f (61.7 MB)
    float*  uhT = ws + 375040;                    // overlays h1n+h2n+hcn (dead by k_uhat)

    k_t_w1<<<41, 256, 0, stream>>>(w1, w1T);
    k_t_w2b<<<800, 256, 0, stream>>>(w2, w2b);
    k_t_wcb<<<2048, 256, 0, stream>>>(wc, wcb);
    k_conv1_pool<<<dim3(42, 64), 256, 0, stream>>>(x, w1T, b1, h1n);
    k_conv2<<<dim3(10, 64), 256, 0, stream>>>(h1n, w2b, b2, h2n);
    k_convcaps<<<dim3(4, 64), 256, 0, stream>>>(h2n, wcb, bc, hcn);
    k_squash<<<dim3(64, 128), 256, 0, stream>>>(hcn, u);
    k_uhat<<<dim3(16, 10, 4), 256, 0, stream>>>(u, Wr, uhT);
    k_route_s<<<dim3(64, 10), 256, 0, stream>>>(uhT, bl, vv, out, 1, 0);
    k_route_b<<<dim3(64, 10), 256, 0, stream>>>(uhT, vv, bl, 1);
    k_route_s<<<dim3(64, 10), 256, 0, stream>>>(uhT, bl, vv, out, 0, 0);
    k_route_b<<<dim3(64, 10), 256, 0, stream>>>(uhT, vv, bl, 0);
    k_route_s<<<dim3(64, 10), 256, 0, stream>>>(uhT, bl, vv, out, 0, 1);
}